// Round 1
// baseline (235.439 us; speedup 1.0000x reference)
//
#include <hip/hip_runtime.h>
#include <hip/hip_bf16.h>

// ============================================================================
// Key insight: indices ∈ [0, 64), so the entire backbone (maps->fc1->fc2->fc3
// ->bn) and the hypernetwork weights theta_e/theta_f have only 64 distinct
// rows ("classes"). We compute them once per class (7 MB total, L2-resident),
// bucket the 8192 batches by class, and run only the tiny per-batch MLPs
// (e-net 2->64->64->16 on S and G, f-net 32->128->128->8) with class-shared
// weights. Total ~0.65 GFLOP vs ~30 GFLOP naive + ~900 MB HBM avoided.
// ============================================================================

#define LEAKY 0.2f
#define NCLS 64
#define B_TOT 8192
#define NSLICE 8   // class slices for func kernel -> 64*8 = 512 blocks

// theta_e layout (per class, 5456 floats, 5392 used):
//   W1e [0,128)  (2x64)   b1e [128,192)
//   W2e [192,4288) (64x64) b2e [4288,4352)
//   W3e [4352,5376) (64x16) b3e [5376,5392)
// theta_f layout (per class, 21768 floats):
//   W1f [0,4096)  (32x128)  b1f [4096,4224)
//   W2f [4224,20608) (128x128) b2f [20608,20736)
//   W3f [20736,21760) (128x8)  b3f [21760,21768)

__device__ __forceinline__ float lrelu(float x) { return x >= 0.f ? x : LEAKY * x; }

// ---------------------------------------------------------------------------
// K1: backbone for the 64 unique maps -> z (64 x 32)
// ---------------------------------------------------------------------------
__global__ __launch_bounds__(256) void backbone_kernel(
    const float* __restrict__ maps,
    const float* __restrict__ fc1_w, const float* __restrict__ fc1_b,
    const float* __restrict__ fc2_w, const float* __restrict__ fc2_b,
    const float* __restrict__ fc3_w, const float* __restrict__ fc3_b,
    const float* __restrict__ bn_w,  const float* __restrict__ bn_b,
    float* __restrict__ z)
{
    __shared__ float m[1024];
    __shared__ float h1[256];
    __shared__ float h2[128];
    __shared__ float h3[128];
    const int c = blockIdx.x;
    const int t = threadIdx.x;

    // C=1, so transpose(0,2,3,1) flatten == plain flatten of maps[c]
    ((float4*)m)[t] = ((const float4*)(maps + c * 1024))[t];
    __syncthreads();

    // fc1: 1024 -> 256 (leaky)
    {
        float acc = fc1_b[t];
#pragma unroll 8
        for (int i = 0; i < 1024; ++i) acc += m[i] * fc1_w[i * 256 + t];
        h1[t] = lrelu(acc);
    }
    __syncthreads();
    // fc2: 256 -> 128 (leaky)
    if (t < 128) {
        float acc = fc2_b[t];
#pragma unroll 8
        for (int i = 0; i < 256; ++i) acc += h1[i] * fc2_w[i * 128 + t];
        h2[t] = lrelu(acc);
    }
    __syncthreads();
    // fc3: 128 -> 128 (leaky)
    if (t < 128) {
        float acc = fc3_b[t];
#pragma unroll 8
        for (int i = 0; i < 128; ++i) acc += h2[i] * fc3_w[i * 128 + t];
        h3[t] = lrelu(acc);
    }
    __syncthreads();
    // bn: 128 -> 32 (NO activation)
    if (t < 32) {
        float acc = bn_b[t];
#pragma unroll 8
        for (int i = 0; i < 128; ++i) acc += h3[i] * bn_w[i * 32 + t];
        z[c * 32 + t] = acc;
    }
}

// ---------------------------------------------------------------------------
// K2: theta_e = z@e_w + e_b ; theta_f = z@f_w + f_b  (per class)
// grid: (ceil(27224/256), 64)
// ---------------------------------------------------------------------------
__global__ __launch_bounds__(256) void theta_kernel(
    const float* __restrict__ z,
    const float* __restrict__ e_w, const float* __restrict__ e_b,
    const float* __restrict__ f_w, const float* __restrict__ f_b,
    float* __restrict__ th_e, float* __restrict__ th_f)
{
    const int c = blockIdx.y;
    int j = blockIdx.x * 256 + threadIdx.x;
    __shared__ float zc[32];
    if (threadIdx.x < 32) zc[threadIdx.x] = z[c * 32 + threadIdx.x];
    __syncthreads();

    if (j < 5456) {
        float acc = e_b[j];
#pragma unroll
        for (int k = 0; k < 32; ++k) acc += zc[k] * e_w[k * 5456 + j];
        th_e[c * 5456 + j] = acc;
    } else {
        j -= 5456;
        if (j < 21768) {
            float acc = f_b[j];
#pragma unroll
            for (int k = 0; k < 32; ++k) acc += zc[k] * f_w[k * 21768 + j];
            th_f[c * 21768 + j] = acc;
        }
    }
}

// ---------------------------------------------------------------------------
// K3: bucket batches by class: count -> scan -> scatter
// ---------------------------------------------------------------------------
__global__ __launch_bounds__(256) void count_kernel(const int* __restrict__ idx,
                                                    int* __restrict__ counts)
{
    int b = blockIdx.x * 256 + threadIdx.x;
    if (b < B_TOT) atomicAdd(&counts[idx[b]], 1);
}

__global__ void scan_kernel(const int* __restrict__ counts, int* __restrict__ offsets)
{
    if (threadIdx.x == 0) {
        int s = 0;
        for (int c = 0; c < NCLS; ++c) { offsets[c] = s; s += counts[c]; }
    }
}

__global__ __launch_bounds__(256) void scatter_kernel(
    const int* __restrict__ idx, const int* __restrict__ offsets,
    int* __restrict__ cursor, int* __restrict__ perm)
{
    int b = blockIdx.x * 256 + threadIdx.x;
    if (b < B_TOT) {
        int c = idx[b];
        int p = offsets[c] + atomicAdd(&cursor[c], 1);
        perm[p] = b;
    }
}

// ---------------------------------------------------------------------------
// K4: per-batch func MLPs with class-shared theta.
// grid (64, NSLICE), 256 threads (4 waves). Each wave processes tiles of
// TB=4 batches (register-tiled so each weight load feeds 4 FMAs).
// ---------------------------------------------------------------------------
__global__ __launch_bounds__(256) void func_kernel(
    const float* __restrict__ states,
    const float* __restrict__ th_e_all, const float* __restrict__ th_f_all,
    const int* __restrict__ counts, const int* __restrict__ offsets,
    const int* __restrict__ perm, float* __restrict__ out)
{
    const int c    = blockIdx.x;
    const int s    = blockIdx.y;
    const int nb   = counts[c];
    const int base = offsets[c];
    const int chunk = (nb + NSLICE - 1) / NSLICE;
    const int k0 = s * chunk;
    const int k1 = (nb < k0 + chunk) ? nb : (k0 + chunk);
    const int cnt = (k1 > k0) ? (k1 - k0) : 0;

    const float* te = th_e_all + c * 5456;
    const float* tf = th_f_all + c * 21768;

    const int wid  = threadIdx.x >> 6;
    const int lane = threadIdx.x & 63;

    // per-wave scratch (no cross-wave sharing)
    __shared__ float stgA[4][4 * 64];    // e-net stage
    __shared__ float zfb [4][4 * 32];    // zf = [e_s, e_g]
    __shared__ float stgF[4][4 * 128];   // f-net y1
    __shared__ float stgG[4][4 * 128];   // f-net y2

    const int ntiles = (cnt + 3) >> 2;
    const int iters  = (ntiles + 3) >> 2;   // uniform across block (4 waves)

    for (int q = 0; q < iters; ++q) {
        const int tile = q * 4 + wid;
        const int tb0  = k0 + tile * 4;

        int   bi[4];
        bool  val[4];
        float S0[4], S1[4], G0[4], G1[4];
#pragma unroll
        for (int j = 0; j < 4; ++j) {
            int kk = tb0 + j;
            val[j] = (tile < ntiles) && (kk < k1);
            bi[j]  = val[j] ? perm[base + kk] : 0;
            S0[j] = states[bi[j] * 4 + 0];
            S1[j] = states[bi[j] * 4 + 1];
            G0[j] = states[bi[j] * 4 + 2];
            G1[j] = states[bi[j] * 4 + 3];
        }

        // ---------------- e-net, v=0 uses S, v=1 uses G ----------------
        for (int v = 0; v < 2; ++v) {
            float i0[4], i1[4];
#pragma unroll
            for (int j = 0; j < 4; ++j) {
                i0[j] = v ? G0[j] : S0[j];
                i1[j] = v ? G1[j] : S1[j];
            }
            // L1: 2 -> 64 (leaky), lane o = lane
            {
                float w0 = te[lane], w1 = te[64 + lane], b1 = te[128 + lane];
#pragma unroll
                for (int j = 0; j < 4; ++j)
                    stgA[wid][j * 64 + lane] = lrelu(i0[j] * w0 + i1[j] * w1 + b1);
            }
            __syncthreads();
            // L2: 64 -> 64 (leaky)
            {
                float b2 = te[4288 + lane];
                float a0 = b2, a1 = b2, a2 = b2, a3 = b2;
#pragma unroll 8
                for (int i = 0; i < 64; ++i) {
                    float w = te[192 + i * 64 + lane];
                    a0 += stgA[wid][0 * 64 + i] * w;
                    a1 += stgA[wid][1 * 64 + i] * w;
                    a2 += stgA[wid][2 * 64 + i] * w;
                    a3 += stgA[wid][3 * 64 + i] * w;
                }
                __syncthreads();
                stgA[wid][0 * 64 + lane] = lrelu(a0);
                stgA[wid][1 * 64 + lane] = lrelu(a1);
                stgA[wid][2 * 64 + lane] = lrelu(a2);
                stgA[wid][3 * 64 + lane] = lrelu(a3);
            }
            __syncthreads();
            // L3: 64 -> 16 (no activation) -> zf[v*16 + o]
            if (lane < 16) {
                float b3 = te[5376 + lane];
                float a0 = b3, a1 = b3, a2 = b3, a3 = b3;
#pragma unroll 8
                for (int i = 0; i < 64; ++i) {
                    float w = te[4352 + i * 16 + lane];
                    a0 += stgA[wid][0 * 64 + i] * w;
                    a1 += stgA[wid][1 * 64 + i] * w;
                    a2 += stgA[wid][2 * 64 + i] * w;
                    a3 += stgA[wid][3 * 64 + i] * w;
                }
                zfb[wid][0 * 32 + v * 16 + lane] = a0;
                zfb[wid][1 * 32 + v * 16 + lane] = a1;
                zfb[wid][2 * 32 + v * 16 + lane] = a2;
                zfb[wid][3 * 32 + v * 16 + lane] = a3;
            }
            __syncthreads();
        }

        // ---------------- f-net: 32 -> 128 -> 128 -> 8 ----------------
        // L1: 32 -> 128 (leaky); lane handles cols lane and lane+64
        {
            float bb0 = tf[4096 + lane], bb1 = tf[4096 + 64 + lane];
            float a0[4], a1[4];
#pragma unroll
            for (int j = 0; j < 4; ++j) { a0[j] = bb0; a1[j] = bb1; }
#pragma unroll 4
            for (int i = 0; i < 32; ++i) {
                float w0 = tf[i * 128 + lane];
                float w1 = tf[i * 128 + 64 + lane];
#pragma unroll
                for (int j = 0; j < 4; ++j) {
                    float y = zfb[wid][j * 32 + i];
                    a0[j] += y * w0;
                    a1[j] += y * w1;
                }
            }
#pragma unroll
            for (int j = 0; j < 4; ++j) {
                stgF[wid][j * 128 + lane]      = lrelu(a0[j]);
                stgF[wid][j * 128 + 64 + lane] = lrelu(a1[j]);
            }
        }
        __syncthreads();
        // L2: 128 -> 128 (leaky)
        {
            float bb0 = tf[20608 + lane], bb1 = tf[20608 + 64 + lane];
            float a0[4], a1[4];
#pragma unroll
            for (int j = 0; j < 4; ++j) { a0[j] = bb0; a1[j] = bb1; }
#pragma unroll 4
            for (int i = 0; i < 128; ++i) {
                float w0 = tf[4224 + i * 128 + lane];
                float w1 = tf[4224 + i * 128 + 64 + lane];
#pragma unroll
                for (int j = 0; j < 4; ++j) {
                    float y = stgF[wid][j * 128 + i];
                    a0[j] += y * w0;
                    a1[j] += y * w1;
                }
            }
#pragma unroll
            for (int j = 0; j < 4; ++j) {
                stgG[wid][j * 128 + lane]      = lrelu(a0[j]);
                stgG[wid][j * 128 + 64 + lane] = lrelu(a1[j]);
            }
        }
        __syncthreads();
        // L3: 128 -> 8 (no activation), then sin/cos output
        if (lane < 8) {
            float b3 = tf[21760 + lane];
            float a0 = b3, a1 = b3, a2 = b3, a3 = b3;
#pragma unroll 8
            for (int i = 0; i < 128; ++i) {
                float w = tf[20736 + i * 8 + lane];
                a0 += stgG[wid][0 * 128 + i] * w;
                a1 += stgG[wid][1 * 128 + i] * w;
                a2 += stgG[wid][2 * 128 + i] * w;
                a3 += stgG[wid][3 * 128 + i] * w;
            }
            float ang[4] = {a0, a1, a2, a3};
#pragma unroll
            for (int j = 0; j < 4; ++j) {
                if (val[j]) {
                    out[bi[j] * 16 + lane]     = __sinf(ang[j]);
                    out[bi[j] * 16 + 8 + lane] = __cosf(ang[j]);
                }
            }
        }
        __syncthreads();
    }
}

// ---------------------------------------------------------------------------
extern "C" void kernel_launch(void* const* d_in, const int* in_sizes, int n_in,
                              void* d_out, int out_size, void* d_ws, size_t ws_size,
                              hipStream_t stream)
{
    const int*   indices = (const int*)  d_in[0];
    const float* states  = (const float*)d_in[1];
    const float* maps    = (const float*)d_in[2];
    const float* fc1_w   = (const float*)d_in[3];
    const float* fc1_b   = (const float*)d_in[4];
    const float* fc2_w   = (const float*)d_in[5];
    const float* fc2_b   = (const float*)d_in[6];
    const float* fc3_w   = (const float*)d_in[7];
    const float* fc3_b   = (const float*)d_in[8];
    const float* bn_w    = (const float*)d_in[9];
    const float* bn_b    = (const float*)d_in[10];
    const float* e_w     = (const float*)d_in[11];
    const float* e_b     = (const float*)d_in[12];
    const float* f_w     = (const float*)d_in[13];
    const float* f_b     = (const float*)d_in[14];
    float* out = (float*)d_out;

    // workspace layout (floats)
    float* ws   = (float*)d_ws;
    float* z    = ws;                 // 64*32      = 2048
    float* th_e = ws + 2048;          // 64*5456    = 349184
    float* th_f = ws + 351232;        // 64*21768   = 1393152
    int* counts  = (int*)(ws + 1744384); // 64
    int* cursor  = counts + 64;          // 64
    int* offsets = counts + 128;         // 64
    int* perm    = counts + 192;         // 8192
    // total: (1744384 + 192 + 8192) * 4 B ≈ 7.0 MB

    hipMemsetAsync(counts, 0, 128 * sizeof(int), stream);  // counts + cursor

    backbone_kernel<<<NCLS, 256, 0, stream>>>(maps, fc1_w, fc1_b, fc2_w, fc2_b,
                                              fc3_w, fc3_b, bn_w, bn_b, z);

    theta_kernel<<<dim3((5456 + 21768 + 255) / 256, NCLS), 256, 0, stream>>>(
        z, e_w, e_b, f_w, f_b, th_e, th_f);

    count_kernel<<<B_TOT / 256, 256, 0, stream>>>(indices, counts);
    scan_kernel<<<1, 64, 0, stream>>>(counts, offsets);
    scatter_kernel<<<B_TOT / 256, 256, 0, stream>>>(indices, offsets, cursor, perm);

    func_kernel<<<dim3(NCLS, NSLICE), 256, 0, stream>>>(
        states, th_e, th_f, counts, offsets, perm, out);
}

// Round 2
// 180.896 us; speedup vs baseline: 1.3015x; 1.3015x over previous
//
#include <hip/hip_runtime.h>
#include <hip/hip_bf16.h>

// ============================================================================
// indices ∈ [0,64) => backbone + theta have only 64 distinct rows. Compute
// per-class (7 MB, L2-resident), bucket batches by class, run only the tiny
// per-batch MLPs with class-shared weights.
// R1 fixes: backbone was 77us latency-bound (1 wave/CU, 1024-deep serial load
// chain). Split into fc1 (64x8 grid, 8-way K-split) + mid (fused fc2/fc3/bn,
// 512 thr, 4-way K-split). Theta loop flipped (weights in regs, classes inner)
// to cut 224MB L2 traffic to 10MB. count/scan/scatter fused into one
// single-block bucket kernel. func LDS reads vectorized to float4.
// ============================================================================

#define LEAKY 0.2f
#define NCLS 64
#define B_TOT 8192
#define NSLICE 8

// theta_e layout (per class, 5456 floats): W1e[0,128) b1e[128,192)
//   W2e[192,4288) b2e[4288,4352) W3e[4352,5376) b3e[5376,5392)
// theta_f layout (per class, 21768 floats): W1f[0,4096) b1f[4096,4224)
//   W2f[4224,20608) b2f[20608,20736) W3f[20736,21760) b3f[21760,21768)

__device__ __forceinline__ float lrelu(float x) { return x >= 0.f ? x : LEAKY * x; }

// ---------------------------------------------------------------------------
// K1: fc1 (1024 -> 256, leaky) for 64 classes. grid (64, 8): block = class c,
// out-slice s (32 outputs). 256 thr = 32 outs x 8 k-slices of 128.
// ---------------------------------------------------------------------------
__global__ __launch_bounds__(256) void fc1_kernel(
    const float* __restrict__ maps,
    const float* __restrict__ fc1_w, const float* __restrict__ fc1_b,
    float* __restrict__ h1g)
{
    __shared__ __align__(16) float m[1024];
    __shared__ float red[256];
    const int c = blockIdx.x;
    const int s = blockIdx.y;
    const int t = threadIdx.x;

    // C=1: transpose(0,2,3,1) flatten == plain flatten
    ((float4*)m)[t] = ((const float4*)(maps + c * 1024))[t];
    __syncthreads();

    const int o  = t & 31;
    const int ks = t >> 5;
    const int og = s * 32 + o;
    const float* wp = fc1_w + og;
    float acc = 0.f;
#pragma unroll 16
    for (int i = 0; i < 128; ++i) {
        const int k = ks * 128 + i;
        acc += m[k] * wp[k * 256];
    }
    red[t] = acc;
    __syncthreads();
    if (t < 32) {
        float a = fc1_b[og];
#pragma unroll
        for (int r = 0; r < 8; ++r) a += red[r * 32 + t];
        h1g[c * 256 + og] = lrelu(a);
    }
}

// ---------------------------------------------------------------------------
// K2: fused fc2 (256->128,leaky) + fc3 (128->128,leaky) + bn (128->32).
// grid 64 (one class/block), 512 threads, K-split reductions in LDS.
// ---------------------------------------------------------------------------
__global__ __launch_bounds__(512) void mid_kernel(
    const float* __restrict__ h1g,
    const float* __restrict__ fc2_w, const float* __restrict__ fc2_b,
    const float* __restrict__ fc3_w, const float* __restrict__ fc3_b,
    const float* __restrict__ bn_w,  const float* __restrict__ bn_b,
    float* __restrict__ z)
{
    __shared__ float h1[256];
    __shared__ float red[512];
    __shared__ float h2[128];
    __shared__ float h3[128];
    const int c = blockIdx.x;
    const int t = threadIdx.x;
    if (t < 256) h1[t] = h1g[c * 256 + t];
    __syncthreads();
    // fc2: 128 outs x 4 k-slices of 64
    {
        const int o = t & 127, ks = t >> 7;
        float acc = 0.f;
#pragma unroll 16
        for (int i = 0; i < 64; ++i) {
            const int k = ks * 64 + i;
            acc += h1[k] * fc2_w[k * 128 + o];
        }
        red[t] = acc;
    }
    __syncthreads();
    if (t < 128) h2[t] = lrelu(fc2_b[t] + red[t] + red[128 + t] + red[256 + t] + red[384 + t]);
    __syncthreads();
    // fc3: 128 outs x 4 k-slices of 32
    {
        const int o = t & 127, ks = t >> 7;
        float acc = 0.f;
#pragma unroll
        for (int i = 0; i < 32; ++i) {
            const int k = ks * 32 + i;
            acc += h2[k] * fc3_w[k * 128 + o];
        }
        red[t] = acc;
    }
    __syncthreads();
    if (t < 128) h3[t] = lrelu(fc3_b[t] + red[t] + red[128 + t] + red[256 + t] + red[384 + t]);
    __syncthreads();
    // bn: 32 outs x 16 k-slices of 8 (no activation)
    {
        const int o = t & 31, ks = t >> 5;
        float acc = 0.f;
#pragma unroll
        for (int i = 0; i < 8; ++i) {
            const int k = ks * 8 + i;
            acc += h3[k] * bn_w[k * 32 + o];
        }
        red[t] = acc;
    }
    __syncthreads();
    if (t < 32) {
        float a = bn_b[t];
#pragma unroll
        for (int r = 0; r < 16; ++r) a += red[r * 32 + t];
        z[c * 32 + t] = a;
    }
}

// ---------------------------------------------------------------------------
// K3: theta = z @ [e_w | f_w] + bias, loop-flipped: thread owns column j,
// keeps its 32 weights in registers, iterates all 64 classes (z in LDS).
// Each weight element read exactly once from global.
// ---------------------------------------------------------------------------
__global__ __launch_bounds__(256) void theta_kernel(
    const float* __restrict__ z,
    const float* __restrict__ e_w, const float* __restrict__ e_b,
    const float* __restrict__ f_w, const float* __restrict__ f_b,
    float* __restrict__ th_e, float* __restrict__ th_f)
{
    __shared__ __align__(16) float zl[2048];
    const int t = threadIdx.x;
    ((float4*)zl)[t]       = ((const float4*)z)[t];
    ((float4*)zl)[t + 256] = ((const float4*)z)[t + 256];
    __syncthreads();

    int j = blockIdx.x * 256 + t;
    const float* wbase;
    float* op;
    int stride, ostride;
    float bias;
    if (j < 5456) {
        wbase = e_w + j; bias = e_b[j]; op = th_e + j;
        stride = 5456; ostride = 5456;
    } else {
        const int jj = j - 5456;
        if (jj >= 21768) return;
        wbase = f_w + jj; bias = f_b[jj]; op = th_f + jj;
        stride = 21768; ostride = 21768;
    }
    float wk[32];
#pragma unroll
    for (int k = 0; k < 32; ++k) wk[k] = wbase[k * stride];

#pragma unroll 1
    for (int c0 = 0; c0 < 64; c0 += 4) {
        float a0 = bias, a1 = bias, a2 = bias, a3 = bias;
#pragma unroll
        for (int k4 = 0; k4 < 8; ++k4) {
            const float4 z0 = *(const float4*)&zl[(c0 + 0) * 32 + k4 * 4];
            const float4 z1 = *(const float4*)&zl[(c0 + 1) * 32 + k4 * 4];
            const float4 z2 = *(const float4*)&zl[(c0 + 2) * 32 + k4 * 4];
            const float4 z3 = *(const float4*)&zl[(c0 + 3) * 32 + k4 * 4];
            const float w0 = wk[k4 * 4], w1 = wk[k4 * 4 + 1];
            const float w2 = wk[k4 * 4 + 2], w3 = wk[k4 * 4 + 3];
            a0 += z0.x * w0 + z0.y * w1 + z0.z * w2 + z0.w * w3;
            a1 += z1.x * w0 + z1.y * w1 + z1.z * w2 + z1.w * w3;
            a2 += z2.x * w0 + z2.y * w1 + z2.z * w2 + z2.w * w3;
            a3 += z3.x * w0 + z3.y * w1 + z3.z * w2 + z3.w * w3;
        }
        op[(c0 + 0) * ostride] = a0;
        op[(c0 + 1) * ostride] = a1;
        op[(c0 + 2) * ostride] = a2;
        op[(c0 + 3) * ostride] = a3;
    }
}

// ---------------------------------------------------------------------------
// K4: bucket batches by class in ONE block: LDS histogram -> wave shfl-scan
// -> LDS-cursor scatter. Replaces memset+count+scan+scatter.
// ---------------------------------------------------------------------------
__global__ __launch_bounds__(1024) void bucket_kernel(
    const int* __restrict__ idx, int* __restrict__ counts,
    int* __restrict__ offsets, int* __restrict__ perm)
{
    __shared__ int cnt[64];
    const int t = threadIdx.x;
    if (t < 64) cnt[t] = 0;
    __syncthreads();
    int myidx[8];
#pragma unroll
    for (int r = 0; r < 8; ++r) {
        myidx[r] = idx[r * 1024 + t];
        atomicAdd(&cnt[myidx[r]], 1);
    }
    __syncthreads();
    if (t < 64) {          // single wave: exclusive prefix scan
        const int v = cnt[t];
        int x = v;
        for (int d = 1; d < 64; d <<= 1) {
            const int y = __shfl_up(x, d, 64);
            if (t >= d) x += y;
        }
        counts[t]  = v;
        offsets[t] = x - v;
        cnt[t]     = x - v;   // becomes cursor
    }
    __syncthreads();
#pragma unroll
    for (int r = 0; r < 8; ++r) {
        const int p = atomicAdd(&cnt[myidx[r]], 1);
        perm[p] = r * 1024 + t;
    }
}

// ---------------------------------------------------------------------------
// K5: per-batch func MLPs with class-shared theta. grid (64, NSLICE), 256 thr
// (4 waves), each wave register-tiles 4 batches. LDS activation reads float4.
// ---------------------------------------------------------------------------
__global__ __launch_bounds__(256) void func_kernel(
    const float* __restrict__ states,
    const float* __restrict__ th_e_all, const float* __restrict__ th_f_all,
    const int* __restrict__ counts, const int* __restrict__ offsets,
    const int* __restrict__ perm, float* __restrict__ out)
{
    const int c    = blockIdx.x;
    const int s    = blockIdx.y;
    const int nb   = counts[c];
    const int base = offsets[c];
    const int chunk = (nb + NSLICE - 1) / NSLICE;
    const int k0 = s * chunk;
    const int k1 = (nb < k0 + chunk) ? nb : (k0 + chunk);
    const int cnt = (k1 > k0) ? (k1 - k0) : 0;

    const float* te = th_e_all + c * 5456;
    const float* tf = th_f_all + c * 21768;

    const int wid  = threadIdx.x >> 6;
    const int lane = threadIdx.x & 63;

    __shared__ __align__(16) float stgA[4][4 * 64];
    __shared__ __align__(16) float zfb [4][4 * 32];
    __shared__ __align__(16) float stgF[4][4 * 128];
    __shared__ __align__(16) float stgG[4][4 * 128];

    const int ntiles = (cnt + 3) >> 2;
    const int iters  = (ntiles + 3) >> 2;

    for (int q = 0; q < iters; ++q) {
        const int tile = q * 4 + wid;
        const int tb0  = k0 + tile * 4;

        int   bi[4];
        bool  val[4];
        float S0[4], S1[4], G0[4], G1[4];
#pragma unroll
        for (int j = 0; j < 4; ++j) {
            const int kk = tb0 + j;
            val[j] = (tile < ntiles) && (kk < k1);
            bi[j]  = val[j] ? perm[base + kk] : 0;
            S0[j] = states[bi[j] * 4 + 0];
            S1[j] = states[bi[j] * 4 + 1];
            G0[j] = states[bi[j] * 4 + 2];
            G1[j] = states[bi[j] * 4 + 3];
        }

        // ---------------- e-net (v=0: S, v=1: G) ----------------
        for (int v = 0; v < 2; ++v) {
            // L1: 2 -> 64 (leaky)
            {
                const float w0 = te[lane], w1 = te[64 + lane], b1 = te[128 + lane];
#pragma unroll
                for (int j = 0; j < 4; ++j) {
                    const float i0 = v ? G0[j] : S0[j];
                    const float i1 = v ? G1[j] : S1[j];
                    stgA[wid][j * 64 + lane] = lrelu(i0 * w0 + i1 * w1 + b1);
                }
            }
            __syncthreads();
            // L2: 64 -> 64 (leaky)
            {
                const float b2 = te[4288 + lane];
                float a0 = b2, a1 = b2, a2 = b2, a3 = b2;
#pragma unroll 4
                for (int i4 = 0; i4 < 16; ++i4) {
                    const float4 y0 = *(const float4*)&stgA[wid][0 * 64 + i4 * 4];
                    const float4 y1 = *(const float4*)&stgA[wid][1 * 64 + i4 * 4];
                    const float4 y2 = *(const float4*)&stgA[wid][2 * 64 + i4 * 4];
                    const float4 y3 = *(const float4*)&stgA[wid][3 * 64 + i4 * 4];
#pragma unroll
                    for (int u = 0; u < 4; ++u) {
                        const float w = te[192 + (i4 * 4 + u) * 64 + lane];
                        a0 += (&y0.x)[u] * w;
                        a1 += (&y1.x)[u] * w;
                        a2 += (&y2.x)[u] * w;
                        a3 += (&y3.x)[u] * w;
                    }
                }
                __syncthreads();
                stgA[wid][0 * 64 + lane] = lrelu(a0);
                stgA[wid][1 * 64 + lane] = lrelu(a1);
                stgA[wid][2 * 64 + lane] = lrelu(a2);
                stgA[wid][3 * 64 + lane] = lrelu(a3);
            }
            __syncthreads();
            // L3: 64 -> 16 (no act) -> zf[v*16+o]
            if (lane < 16) {
                const float b3 = te[5376 + lane];
                float a0 = b3, a1 = b3, a2 = b3, a3 = b3;
#pragma unroll 4
                for (int i4 = 0; i4 < 16; ++i4) {
                    const float4 y0 = *(const float4*)&stgA[wid][0 * 64 + i4 * 4];
                    const float4 y1 = *(const float4*)&stgA[wid][1 * 64 + i4 * 4];
                    const float4 y2 = *(const float4*)&stgA[wid][2 * 64 + i4 * 4];
                    const float4 y3 = *(const float4*)&stgA[wid][3 * 64 + i4 * 4];
#pragma unroll
                    for (int u = 0; u < 4; ++u) {
                        const float w = te[4352 + (i4 * 4 + u) * 16 + lane];
                        a0 += (&y0.x)[u] * w;
                        a1 += (&y1.x)[u] * w;
                        a2 += (&y2.x)[u] * w;
                        a3 += (&y3.x)[u] * w;
                    }
                }
                zfb[wid][0 * 32 + v * 16 + lane] = a0;
                zfb[wid][1 * 32 + v * 16 + lane] = a1;
                zfb[wid][2 * 32 + v * 16 + lane] = a2;
                zfb[wid][3 * 32 + v * 16 + lane] = a3;
            }
            __syncthreads();
        }

        // ---------------- f-net: 32 -> 128 -> 128 -> 8 ----------------
        // L1: 32 -> 128 (leaky); lane covers cols lane, lane+64
        {
            const float bb0 = tf[4096 + lane], bb1 = tf[4160 + lane];
            float a0[4], a1[4];
#pragma unroll
            for (int j = 0; j < 4; ++j) { a0[j] = bb0; a1[j] = bb1; }
#pragma unroll 2
            for (int i4 = 0; i4 < 8; ++i4) {
                const float4 y0 = *(const float4*)&zfb[wid][0 * 32 + i4 * 4];
                const float4 y1 = *(const float4*)&zfb[wid][1 * 32 + i4 * 4];
                const float4 y2 = *(const float4*)&zfb[wid][2 * 32 + i4 * 4];
                const float4 y3 = *(const float4*)&zfb[wid][3 * 32 + i4 * 4];
#pragma unroll
                for (int u = 0; u < 4; ++u) {
                    const int i = i4 * 4 + u;
                    const float w0 = tf[i * 128 + lane];
                    const float w1 = tf[i * 128 + 64 + lane];
                    a0[0] += (&y0.x)[u] * w0; a1[0] += (&y0.x)[u] * w1;
                    a0[1] += (&y1.x)[u] * w0; a1[1] += (&y1.x)[u] * w1;
                    a0[2] += (&y2.x)[u] * w0; a1[2] += (&y2.x)[u] * w1;
                    a0[3] += (&y3.x)[u] * w0; a1[3] += (&y3.x)[u] * w1;
                }
            }
#pragma unroll
            for (int j = 0; j < 4; ++j) {
                stgF[wid][j * 128 + lane]      = lrelu(a0[j]);
                stgF[wid][j * 128 + 64 + lane] = lrelu(a1[j]);
            }
        }
        __syncthreads();
        // L2: 128 -> 128 (leaky)
        {
            const float bb0 = tf[20608 + lane], bb1 = tf[20672 + lane];
            float a0[4], a1[4];
#pragma unroll
            for (int j = 0; j < 4; ++j) { a0[j] = bb0; a1[j] = bb1; }
#pragma unroll 4
            for (int i4 = 0; i4 < 32; ++i4) {
                const float4 y0 = *(const float4*)&stgF[wid][0 * 128 + i4 * 4];
                const float4 y1 = *(const float4*)&stgF[wid][1 * 128 + i4 * 4];
                const float4 y2 = *(const float4*)&stgF[wid][2 * 128 + i4 * 4];
                const float4 y3 = *(const float4*)&stgF[wid][3 * 128 + i4 * 4];
#pragma unroll
                for (int u = 0; u < 4; ++u) {
                    const int i = i4 * 4 + u;
                    const float w0 = tf[4224 + i * 128 + lane];
                    const float w1 = tf[4224 + i * 128 + 64 + lane];
                    a0[0] += (&y0.x)[u] * w0; a1[0] += (&y0.x)[u] * w1;
                    a0[1] += (&y1.x)[u] * w0; a1[1] += (&y1.x)[u] * w1;
                    a0[2] += (&y2.x)[u] * w0; a1[2] += (&y2.x)[u] * w1;
                    a0[3] += (&y3.x)[u] * w0; a1[3] += (&y3.x)[u] * w1;
                }
            }
#pragma unroll
            for (int j = 0; j < 4; ++j) {
                stgG[wid][j * 128 + lane]      = lrelu(a0[j]);
                stgG[wid][j * 128 + 64 + lane] = lrelu(a1[j]);
            }
        }
        __syncthreads();
        // L3: 128 -> 8 (no act) + sin/cos epilogue
        if (lane < 8) {
            const float b3 = tf[21760 + lane];
            float a0 = b3, a1 = b3, a2 = b3, a3 = b3;
#pragma unroll 4
            for (int i4 = 0; i4 < 32; ++i4) {
                const float4 y0 = *(const float4*)&stgG[wid][0 * 128 + i4 * 4];
                const float4 y1 = *(const float4*)&stgG[wid][1 * 128 + i4 * 4];
                const float4 y2 = *(const float4*)&stgG[wid][2 * 128 + i4 * 4];
                const float4 y3 = *(const float4*)&stgG[wid][3 * 128 + i4 * 4];
#pragma unroll
                for (int u = 0; u < 4; ++u) {
                    const float w = tf[20736 + (i4 * 4 + u) * 8 + lane];
                    a0 += (&y0.x)[u] * w;
                    a1 += (&y1.x)[u] * w;
                    a2 += (&y2.x)[u] * w;
                    a3 += (&y3.x)[u] * w;
                }
            }
            const float ang[4] = {a0, a1, a2, a3};
#pragma unroll
            for (int j = 0; j < 4; ++j) {
                if (val[j]) {
                    out[bi[j] * 16 + lane]     = __sinf(ang[j]);
                    out[bi[j] * 16 + 8 + lane] = __cosf(ang[j]);
                }
            }
        }
        __syncthreads();
    }
}

// ---------------------------------------------------------------------------
extern "C" void kernel_launch(void* const* d_in, const int* in_sizes, int n_in,
                              void* d_out, int out_size, void* d_ws, size_t ws_size,
                              hipStream_t stream)
{
    const int*   indices = (const int*)  d_in[0];
    const float* states  = (const float*)d_in[1];
    const float* maps    = (const float*)d_in[2];
    const float* fc1_w   = (const float*)d_in[3];
    const float* fc1_b   = (const float*)d_in[4];
    const float* fc2_w   = (const float*)d_in[5];
    const float* fc2_b   = (const float*)d_in[6];
    const float* fc3_w   = (const float*)d_in[7];
    const float* fc3_b   = (const float*)d_in[8];
    const float* bn_w    = (const float*)d_in[9];
    const float* bn_b    = (const float*)d_in[10];
    const float* e_w     = (const float*)d_in[11];
    const float* e_b     = (const float*)d_in[12];
    const float* f_w     = (const float*)d_in[13];
    const float* f_b     = (const float*)d_in[14];
    float* out = (float*)d_out;

    // workspace layout (floats)
    float* ws   = (float*)d_ws;
    float* z    = ws;                    // 2048
    float* th_e = ws + 2048;             // 349184
    float* th_f = ws + 351232;           // 1393152
    float* h1g  = ws + 1744384;          // 16384
    int* counts  = (int*)(ws + 1760768); // 64
    int* offsets = counts + 64;          // 64
    int* perm    = counts + 128;         // 8192
    // total ≈ 7.08 MB

    fc1_kernel<<<dim3(NCLS, 8), 256, 0, stream>>>(maps, fc1_w, fc1_b, h1g);
    mid_kernel<<<NCLS, 512, 0, stream>>>(h1g, fc2_w, fc2_b, fc3_w, fc3_b,
                                         bn_w, bn_b, z);
    bucket_kernel<<<1, 1024, 0, stream>>>(indices, counts, offsets, perm);
    theta_kernel<<<(5456 + 21768 + 255) / 256, 256, 0, stream>>>(
        z, e_w, e_b, f_w, f_b, th_e, th_f);
    func_kernel<<<dim3(NCLS, NSLICE), 256, 0, stream>>>(
        states, th_e, th_f, counts, offsets, perm, out);
}

// Round 3
// 145.506 us; speedup vs baseline: 1.6181x; 1.2432x over previous
//
#include <hip/hip_runtime.h>
#include <hip/hip_bf16.h>

// ============================================================================
// indices ∈ [0,64) => backbone + theta have only 64 distinct rows. Compute
// per-class (7 MB, L2-resident), bucket batches by class, run only the tiny
// per-batch MLPs with class-shared weights.
// R2: func was latency-bound (global weight reads, 18% VALUBusy). v3 stages
// theta into LDS per block (layer-wise, W2f in 2 halves), threads = (batch,
// 8-col group) so weight ds_reads are wave-broadcast b128 feeding 32 FMAs.
// bucket: per-wave histograms (no 64-way atomic serialization). theta: class-
// split grid (428 blocks).
// ============================================================================

#define LEAKY 0.2f
#define NCLS 64
#define B_TOT 8192
#define NSLICE 8

// theta_e (per class, 5456 fl): W1e[0,128) b1e[128,192) W2e[192,4288)
//   b2e[4288,4352) W3e[4352,5376) b3e[5376,5392)
// theta_f (per class, 21768 fl): W1f[0,4096) b1f[4096,4224) W2f[4224,20608)
//   b2f[20608,20736) W3f[20736,21760) b3f[21760,21768)

__device__ __forceinline__ float lrelu(float x) { return x >= 0.f ? x : LEAKY * x; }

// ---------------------------------------------------------------------------
// K1: fc1 (1024 -> 256, leaky) for 64 classes. grid (64,8), 256 thr.
// ---------------------------------------------------------------------------
__global__ __launch_bounds__(256) void fc1_kernel(
    const float* __restrict__ maps,
    const float* __restrict__ fc1_w, const float* __restrict__ fc1_b,
    float* __restrict__ h1g)
{
    __shared__ __align__(16) float m[1024];
    __shared__ float red[256];
    const int c = blockIdx.x;
    const int s = blockIdx.y;
    const int t = threadIdx.x;

    ((float4*)m)[t] = ((const float4*)(maps + c * 1024))[t];
    __syncthreads();

    const int o  = t & 31;
    const int ks = t >> 5;
    const int og = s * 32 + o;
    const float* wp = fc1_w + og;
    float acc = 0.f;
#pragma unroll 16
    for (int i = 0; i < 128; ++i) {
        const int k = ks * 128 + i;
        acc += m[k] * wp[k * 256];
    }
    red[t] = acc;
    __syncthreads();
    if (t < 32) {
        float a = fc1_b[og];
#pragma unroll
        for (int r = 0; r < 8; ++r) a += red[r * 32 + t];
        h1g[c * 256 + og] = lrelu(a);
    }
}

// ---------------------------------------------------------------------------
// K2: fused fc2+fc3+bn. grid 64, 512 thr.
// ---------------------------------------------------------------------------
__global__ __launch_bounds__(512) void mid_kernel(
    const float* __restrict__ h1g,
    const float* __restrict__ fc2_w, const float* __restrict__ fc2_b,
    const float* __restrict__ fc3_w, const float* __restrict__ fc3_b,
    const float* __restrict__ bn_w,  const float* __restrict__ bn_b,
    float* __restrict__ z)
{
    __shared__ float h1[256];
    __shared__ float red[512];
    __shared__ float h2[128];
    __shared__ float h3[128];
    const int c = blockIdx.x;
    const int t = threadIdx.x;
    if (t < 256) h1[t] = h1g[c * 256 + t];
    __syncthreads();
    {
        const int o = t & 127, ks = t >> 7;
        float acc = 0.f;
#pragma unroll 16
        for (int i = 0; i < 64; ++i) {
            const int k = ks * 64 + i;
            acc += h1[k] * fc2_w[k * 128 + o];
        }
        red[t] = acc;
    }
    __syncthreads();
    if (t < 128) h2[t] = lrelu(fc2_b[t] + red[t] + red[128 + t] + red[256 + t] + red[384 + t]);
    __syncthreads();
    {
        const int o = t & 127, ks = t >> 7;
        float acc = 0.f;
#pragma unroll
        for (int i = 0; i < 32; ++i) {
            const int k = ks * 32 + i;
            acc += h2[k] * fc3_w[k * 128 + o];
        }
        red[t] = acc;
    }
    __syncthreads();
    if (t < 128) h3[t] = lrelu(fc3_b[t] + red[t] + red[128 + t] + red[256 + t] + red[384 + t]);
    __syncthreads();
    {
        const int o = t & 31, ks = t >> 5;
        float acc = 0.f;
#pragma unroll
        for (int i = 0; i < 8; ++i) {
            const int k = ks * 8 + i;
            acc += h3[k] * bn_w[k * 32 + o];
        }
        red[t] = acc;
    }
    __syncthreads();
    if (t < 32) {
        float a = bn_b[t];
#pragma unroll
        for (int r = 0; r < 16; ++r) a += red[r * 32 + t];
        z[c * 32 + t] = a;
    }
}

// ---------------------------------------------------------------------------
// K3: theta, class-split grid (107, 4): block owns 256 cols x 16 classes.
// Weights in registers, z in LDS.
// ---------------------------------------------------------------------------
__global__ __launch_bounds__(256) void theta_kernel(
    const float* __restrict__ z,
    const float* __restrict__ e_w, const float* __restrict__ e_b,
    const float* __restrict__ f_w, const float* __restrict__ f_b,
    float* __restrict__ th_e, float* __restrict__ th_f)
{
    __shared__ __align__(16) float zl[2048];
    const int t = threadIdx.x;
    ((float4*)zl)[t]       = ((const float4*)z)[t];
    ((float4*)zl)[t + 256] = ((const float4*)z)[t + 256];
    __syncthreads();

    int j = blockIdx.x * 256 + t;
    const int cbase = blockIdx.y * 16;
    const float* wbase;
    float* op;
    int stride;
    float bias;
    if (j < 5456) {
        wbase = e_w + j; bias = e_b[j]; op = th_e + j; stride = 5456;
    } else {
        const int jj = j - 5456;
        if (jj >= 21768) return;
        wbase = f_w + jj; bias = f_b[jj]; op = th_f + jj; stride = 21768;
    }
    float wk[32];
#pragma unroll
    for (int k = 0; k < 32; ++k) wk[k] = wbase[k * stride];

#pragma unroll
    for (int cc = 0; cc < 16; cc += 4) {
        const int c0 = cbase + cc;
        float a0 = bias, a1 = bias, a2 = bias, a3 = bias;
#pragma unroll
        for (int k4 = 0; k4 < 8; ++k4) {
            const float4 z0 = *(const float4*)&zl[(c0 + 0) * 32 + k4 * 4];
            const float4 z1 = *(const float4*)&zl[(c0 + 1) * 32 + k4 * 4];
            const float4 z2 = *(const float4*)&zl[(c0 + 2) * 32 + k4 * 4];
            const float4 z3 = *(const float4*)&zl[(c0 + 3) * 32 + k4 * 4];
            const float w0 = wk[k4 * 4], w1 = wk[k4 * 4 + 1];
            const float w2 = wk[k4 * 4 + 2], w3 = wk[k4 * 4 + 3];
            a0 += z0.x * w0 + z0.y * w1 + z0.z * w2 + z0.w * w3;
            a1 += z1.x * w0 + z1.y * w1 + z1.z * w2 + z1.w * w3;
            a2 += z2.x * w0 + z2.y * w1 + z2.z * w2 + z2.w * w3;
            a3 += z3.x * w0 + z3.y * w1 + z3.z * w2 + z3.w * w3;
        }
        op[(size_t)(c0 + 0) * stride] = a0;
        op[(size_t)(c0 + 1) * stride] = a1;
        op[(size_t)(c0 + 2) * stride] = a2;
        op[(size_t)(c0 + 3) * stride] = a3;
    }
}

// ---------------------------------------------------------------------------
// K4: bucket. 1 block x 1024 thr; per-wave histograms -> wave scan -> per-wave
// cursors (atomic contention only within a wave).
// ---------------------------------------------------------------------------
__global__ __launch_bounds__(1024) void bucket_kernel(
    const int* __restrict__ idx, int* __restrict__ counts,
    int* __restrict__ offsets, int* __restrict__ perm)
{
    __shared__ int cnt[16][64];
    __shared__ int wcur[16][64];
    const int t = threadIdx.x;
    const int w = t >> 6;
    const int l = t & 63;
    cnt[w][l] = 0;
    __syncthreads();
    int my[8];
#pragma unroll
    for (int r = 0; r < 8; ++r) {
        my[r] = idx[r * 1024 + t];
        atomicAdd(&cnt[w][my[r]], 1);
    }
    __syncthreads();
    if (t < 64) {
        int run = 0;
#pragma unroll
        for (int w2 = 0; w2 < 16; ++w2) {
            const int v = cnt[w2][t];
            wcur[w2][t] = run;      // per-wave prefix within class
            run += v;
        }
        counts[t] = run;
        int x = run;                // exclusive scan over classes (one wave)
        for (int d = 1; d < 64; d <<= 1) {
            const int y = __shfl_up(x, d, 64);
            if (t >= d) x += y;
        }
        const int basec = x - run;
        offsets[t] = basec;
#pragma unroll
        for (int w2 = 0; w2 < 16; ++w2) wcur[w2][t] += basec;
    }
    __syncthreads();
#pragma unroll
    for (int r = 0; r < 8; ++r) {
        const int p = atomicAdd(&wcur[w][my[r]], 1);
        perm[p] = r * 1024 + t;
    }
}

// ---------------------------------------------------------------------------
// K5: func v3. grid (64, 8), 256 thr. LDS-staged weights; 16 batches/pass.
// Thread = (batch b = t&15, col-group). e-net: 32 virtual batches (S,G).
// ---------------------------------------------------------------------------
__global__ __launch_bounds__(256) void func_kernel(
    const float* __restrict__ states,
    const float* __restrict__ th_e_all, const float* __restrict__ th_f_all,
    const int* __restrict__ counts, const int* __restrict__ offsets,
    const int* __restrict__ perm, float* __restrict__ out)
{
    __shared__ __align__(16) float wbuf[8192];   // 32 KB staging (layer-wise)
    __shared__ __align__(16) float w3fb[1160];   // b2f | W3f | b3f (persistent)
    __shared__ __align__(16) float actA[2304];   // e-view 32x72 / f-view 16x132
    __shared__ __align__(16) float actB[2304];

    const int c = blockIdx.x;
    const int s = blockIdx.y;
    const int nb   = counts[c];
    const int base = offsets[c];
    const int chunk = (nb + NSLICE - 1) / NSLICE;
    const int k0 = s * chunk;
    const int k1 = (nb < k0 + chunk) ? nb : (k0 + chunk);
    const int cnt = (k1 > k0) ? (k1 - k0) : 0;
    if (cnt == 0) return;

    const float* te = th_e_all + (size_t)c * 5456;
    const float* tf = th_f_all + (size_t)c * 21768;

    const int t  = threadIdx.x;
    const int b  = t & 15;          // batch slot
    const int gf = t >> 4;          // f col-group (16 x 8 cols)
    const int vb = t & 31;          // e virtual batch (b + 16*v)
    const int ve = (t >> 4) & 1;
    const int ge = t >> 5;          // e col-group (8 x 8 cols)
    const int colf = gf * 8;
    const int cole = ge * 8;
    const int eoff = vb * 72;
    const int foff = b * 132;

    // persistent tail: b2f(128) | W3f(1024) | b3f(8)
    for (int j = t * 4; j < 1160; j += 1024)
        *(float4*)&w3fb[j] = *(const float4*)&tf[20608 + j];

    const int passes = (cnt + 15) >> 4;
    for (int p = 0; p < passes; ++p) {
        __syncthreads();   // guard wbuf/act reuse across passes (and w3fb p=0)

        // ---- stage full e-net weights (contiguous te[0..5392)) ----
        for (int j = t * 4; j < 5392; j += 1024)
            *(float4*)&wbuf[j] = *(const float4*)&te[j];
        __syncthreads();

        const int kk = k0 + p * 16 + b;
        const bool valid = kk < k1;
        const int bi = valid ? perm[base + kk] : 0;
        const float2 sv = *(const float2*)&states[(size_t)bi * 4 + 2 * ve];

        // ---- e-L1: 2 -> 64 (leaky) ----
        {
            const float4 wa0 = *(const float4*)&wbuf[cole];
            const float4 wa1 = *(const float4*)&wbuf[cole + 4];
            const float4 wb0 = *(const float4*)&wbuf[64 + cole];
            const float4 wb1 = *(const float4*)&wbuf[64 + cole + 4];
            const float4 bb0 = *(const float4*)&wbuf[128 + cole];
            const float4 bb1 = *(const float4*)&wbuf[128 + cole + 4];
            float4 o0, o1;
            o0.x = lrelu(sv.x * wa0.x + sv.y * wb0.x + bb0.x);
            o0.y = lrelu(sv.x * wa0.y + sv.y * wb0.y + bb0.y);
            o0.z = lrelu(sv.x * wa0.z + sv.y * wb0.z + bb0.z);
            o0.w = lrelu(sv.x * wa0.w + sv.y * wb0.w + bb0.w);
            o1.x = lrelu(sv.x * wa1.x + sv.y * wb1.x + bb1.x);
            o1.y = lrelu(sv.x * wa1.y + sv.y * wb1.y + bb1.y);
            o1.z = lrelu(sv.x * wa1.z + sv.y * wb1.z + bb1.z);
            o1.w = lrelu(sv.x * wa1.w + sv.y * wb1.w + bb1.w);
            *(float4*)&actA[eoff + cole]     = o0;
            *(float4*)&actA[eoff + cole + 4] = o1;
        }
        __syncthreads();

        // ---- e-L2: 64 -> 64 (leaky) ----
        {
            float acc[8] = {0, 0, 0, 0, 0, 0, 0, 0};
#pragma unroll 4
            for (int i4 = 0; i4 < 16; ++i4) {
                const float4 y4 = *(const float4*)&actA[eoff + i4 * 4];
#pragma unroll
                for (int u = 0; u < 4; ++u) {
                    const int row = 192 + (i4 * 4 + u) * 64 + cole;
                    const float4 wA = *(const float4*)&wbuf[row];
                    const float4 wB = *(const float4*)&wbuf[row + 4];
                    const float yv = (&y4.x)[u];
                    acc[0] += yv * wA.x; acc[1] += yv * wA.y;
                    acc[2] += yv * wA.z; acc[3] += yv * wA.w;
                    acc[4] += yv * wB.x; acc[5] += yv * wB.y;
                    acc[6] += yv * wB.z; acc[7] += yv * wB.w;
                }
            }
            const float4 bA = *(const float4*)&wbuf[4288 + cole];
            const float4 bB = *(const float4*)&wbuf[4288 + cole + 4];
            float4 o0, o1;
            o0.x = lrelu(acc[0] + bA.x); o0.y = lrelu(acc[1] + bA.y);
            o0.z = lrelu(acc[2] + bA.z); o0.w = lrelu(acc[3] + bA.w);
            o1.x = lrelu(acc[4] + bB.x); o1.y = lrelu(acc[5] + bB.y);
            o1.z = lrelu(acc[6] + bB.z); o1.w = lrelu(acc[7] + bB.w);
            *(float4*)&actB[eoff + cole]     = o0;
            *(float4*)&actB[eoff + cole + 4] = o1;
        }
        __syncthreads();

        // ---- e-L3: 64 -> 16 (no act) -> zf in actA f-layout ----
        {
            const int col3 = ge * 2;
            float a0 = 0.f, a1 = 0.f;
#pragma unroll 4
            for (int i4 = 0; i4 < 16; ++i4) {
                const float4 y4 = *(const float4*)&actB[eoff + i4 * 4];
#pragma unroll
                for (int u = 0; u < 4; ++u) {
                    const int i = i4 * 4 + u;
                    const float yv = (&y4.x)[u];
                    a0 += yv * wbuf[4352 + i * 16 + col3];
                    a1 += yv * wbuf[4352 + i * 16 + col3 + 1];
                }
            }
            a0 += wbuf[5376 + col3];
            a1 += wbuf[5376 + col3 + 1];
            actA[foff + ve * 16 + col3]     = a0;
            actA[foff + ve * 16 + col3 + 1] = a1;
        }
        __syncthreads();

        // ---- stage f-L1 weights (contiguous tf[0..4224)) ----
        for (int j = t * 4; j < 4224; j += 1024)
            *(float4*)&wbuf[j] = *(const float4*)&tf[j];
        __syncthreads();

        // ---- f-L1: 32 -> 128 (leaky) ----
        {
            float acc[8] = {0, 0, 0, 0, 0, 0, 0, 0};
#pragma unroll
            for (int i4 = 0; i4 < 8; ++i4) {
                const float4 y4 = *(const float4*)&actA[foff + i4 * 4];
#pragma unroll
                for (int u = 0; u < 4; ++u) {
                    const int row = (i4 * 4 + u) * 128 + colf;
                    const float4 wA = *(const float4*)&wbuf[row];
                    const float4 wB = *(const float4*)&wbuf[row + 4];
                    const float yv = (&y4.x)[u];
                    acc[0] += yv * wA.x; acc[1] += yv * wA.y;
                    acc[2] += yv * wA.z; acc[3] += yv * wA.w;
                    acc[4] += yv * wB.x; acc[5] += yv * wB.y;
                    acc[6] += yv * wB.z; acc[7] += yv * wB.w;
                }
            }
            const float4 bA = *(const float4*)&wbuf[4096 + colf];
            const float4 bB = *(const float4*)&wbuf[4096 + colf + 4];
            float4 o0, o1;
            o0.x = lrelu(acc[0] + bA.x); o0.y = lrelu(acc[1] + bA.y);
            o0.z = lrelu(acc[2] + bA.z); o0.w = lrelu(acc[3] + bA.w);
            o1.x = lrelu(acc[4] + bB.x); o1.y = lrelu(acc[5] + bB.y);
            o1.z = lrelu(acc[6] + bB.z); o1.w = lrelu(acc[7] + bB.w);
            *(float4*)&actB[foff + colf]     = o0;
            *(float4*)&actB[foff + colf + 4] = o1;
        }
        __syncthreads();

        // ---- f-L2: 128 -> 128 (leaky), W staged in two 32 KB K-halves ----
        {
            float acc[8] = {0, 0, 0, 0, 0, 0, 0, 0};
#pragma unroll
            for (int h = 0; h < 2; ++h) {
                if (h) __syncthreads();   // drain h0 reads before restage
                for (int j = t * 4; j < 8192; j += 1024)
                    *(float4*)&wbuf[j] = *(const float4*)&tf[4224 + h * 8192 + j];
                __syncthreads();
#pragma unroll 4
                for (int i4 = 0; i4 < 16; ++i4) {
                    const float4 y4 = *(const float4*)&actB[foff + h * 64 + i4 * 4];
#pragma unroll
                    for (int u = 0; u < 4; ++u) {
                        const int row = (i4 * 4 + u) * 128 + colf;
                        const float4 wA = *(const float4*)&wbuf[row];
                        const float4 wB = *(const float4*)&wbuf[row + 4];
                        const float yv = (&y4.x)[u];
                        acc[0] += yv * wA.x; acc[1] += yv * wA.y;
                        acc[2] += yv * wA.z; acc[3] += yv * wA.w;
                        acc[4] += yv * wB.x; acc[5] += yv * wB.y;
                        acc[6] += yv * wB.z; acc[7] += yv * wB.w;
                    }
                }
            }
            const float4 bA = *(const float4*)&w3fb[colf];
            const float4 bB = *(const float4*)&w3fb[colf + 4];
            float4 o0, o1;
            o0.x = lrelu(acc[0] + bA.x); o0.y = lrelu(acc[1] + bA.y);
            o0.z = lrelu(acc[2] + bA.z); o0.w = lrelu(acc[3] + bA.w);
            o1.x = lrelu(acc[4] + bB.x); o1.y = lrelu(acc[5] + bB.y);
            o1.z = lrelu(acc[6] + bB.z); o1.w = lrelu(acc[7] + bB.w);
            *(float4*)&actA[foff + colf]     = o0;
            *(float4*)&actA[foff + colf + 4] = o1;
        }
        __syncthreads();

        // ---- f-L3: 128 -> 8 (no act) + sin/cos ----
        if (gf < 8) {
            float a = 0.f;
#pragma unroll 8
            for (int i4 = 0; i4 < 32; ++i4) {
                const float4 y4 = *(const float4*)&actA[foff + i4 * 4];
#pragma unroll
                for (int u = 0; u < 4; ++u)
                    a += (&y4.x)[u] * w3fb[128 + (i4 * 4 + u) * 8 + gf];
            }
            a += w3fb[1152 + gf];
            if (valid) {
                out[(size_t)bi * 16 + gf]     = __sinf(a);
                out[(size_t)bi * 16 + 8 + gf] = __cosf(a);
            }
        }
    }
}

// ---------------------------------------------------------------------------
extern "C" void kernel_launch(void* const* d_in, const int* in_sizes, int n_in,
                              void* d_out, int out_size, void* d_ws, size_t ws_size,
                              hipStream_t stream)
{
    const int*   indices = (const int*)  d_in[0];
    const float* states  = (const float*)d_in[1];
    const float* maps    = (const float*)d_in[2];
    const float* fc1_w   = (const float*)d_in[3];
    const float* fc1_b   = (const float*)d_in[4];
    const float* fc2_w   = (const float*)d_in[5];
    const float* fc2_b   = (const float*)d_in[6];
    const float* fc3_w   = (const float*)d_in[7];
    const float* fc3_b   = (const float*)d_in[8];
    const float* bn_w    = (const float*)d_in[9];
    const float* bn_b    = (const float*)d_in[10];
    const float* e_w     = (const float*)d_in[11];
    const float* e_b     = (const float*)d_in[12];
    const float* f_w     = (const float*)d_in[13];
    const float* f_b     = (const float*)d_in[14];
    float* out = (float*)d_out;

    float* ws   = (float*)d_ws;
    float* z    = ws;                    // 2048
    float* th_e = ws + 2048;             // 349184
    float* th_f = ws + 351232;           // 1393152
    float* h1g  = ws + 1744384;          // 16384
    int* counts  = (int*)(ws + 1760768); // 64
    int* offsets = counts + 64;          // 64
    int* perm    = counts + 128;         // 8192

    fc1_kernel<<<dim3(NCLS, 8), 256, 0, stream>>>(maps, fc1_w, fc1_b, h1g);
    mid_kernel<<<NCLS, 512, 0, stream>>>(h1g, fc2_w, fc2_b, fc3_w, fc3_b,
                                         bn_w, bn_b, z);
    bucket_kernel<<<1, 1024, 0, stream>>>(indices, counts, offsets, perm);
    theta_kernel<<<dim3((5456 + 21768 + 255) / 256, 4), 256, 0, stream>>>(
        z, e_w, e_b, f_w, f_b, th_e, th_f);
    func_kernel<<<dim3(NCLS, NSLICE), 256, 0, stream>>>(
        states, th_e, th_f, counts, offsets, perm, out);
}

// Round 4
// 141.617 us; speedup vs baseline: 1.6625x; 1.0275x over previous
//
#include <hip/hip_runtime.h>
#include <hip/hip_bf16.h>

// ============================================================================
// indices ∈ [0,64) => backbone + theta have only 64 distinct rows. Compute
// per-class (7 MB, L2-resident), bucket batches by class, run only the tiny
// per-batch MLPs with class-shared weights.
// R4: 3 dispatches. K1 = fused backbone (fc1+fc2+fc3+bn, 1024 thr, 64 blocks)
// + bucket as block 64. K2 = theta (856 blocks, reg-weights). K3 = func v4:
// 512 thr, 32-batch passes, NSLICE=4 (~1 pass/block so weight staging
// amortizes), e-act stride 68 (odd f4 -> conflict-free), W2f staged in 16KB
// K-quarters; total static LDS 61KB.
// ============================================================================

#define LEAKY 0.2f
#define NCLS 64
#define B_TOT 8192
#define NSLICE 4

// theta_e (per class, 5456 fl): W1e[0,128) b1e[128,192) W2e[192,4288)
//   b2e[4288,4352) W3e[4352,5376) b3e[5376,5392)
// theta_f (per class, 21768 fl): W1f[0,4096) b1f[4096,4224) W2f[4224,20608)
//   b2f[20608,20736) W3f[20736,21760) b3f[21760,21768)

__device__ __forceinline__ float lrelu(float x) { return x >= 0.f ? x : LEAKY * x; }

// ---------------------------------------------------------------------------
// K1: blocks 0..63: fused backbone for class c. block 64: bucket.
// 1024 threads.
// ---------------------------------------------------------------------------
__global__ __launch_bounds__(1024) void backbone_bucket_kernel(
    const float* __restrict__ maps,
    const float* __restrict__ fc1_w, const float* __restrict__ fc1_b,
    const float* __restrict__ fc2_w, const float* __restrict__ fc2_b,
    const float* __restrict__ fc3_w, const float* __restrict__ fc3_b,
    const float* __restrict__ bn_w,  const float* __restrict__ bn_b,
    float* __restrict__ z,
    const int* __restrict__ idx, int* __restrict__ counts,
    int* __restrict__ offsets, int* __restrict__ perm)
{
    __shared__ float m[1024];
    __shared__ float red[1024];
    __shared__ float h1[256];
    __shared__ float h2[128];
    __shared__ float h3[128];
    __shared__ int cnt[16][64];
    __shared__ int wcur[16][64];

    const int t = threadIdx.x;

    if (blockIdx.x == 64) {
        // ---------------- bucket ----------------
        const int w = t >> 6;
        cnt[w][t & 63] = 0;
        __syncthreads();
        int my[8];
#pragma unroll
        for (int r = 0; r < 8; ++r) {
            my[r] = idx[r * 1024 + t];
            atomicAdd(&cnt[w][my[r]], 1);
        }
        __syncthreads();
        if (t < 64) {
            int run = 0;
#pragma unroll
            for (int w2 = 0; w2 < 16; ++w2) {
                const int v = cnt[w2][t];
                wcur[w2][t] = run;
                run += v;
            }
            counts[t] = run;
            int x = run;
            for (int d = 1; d < 64; d <<= 1) {
                const int y = __shfl_up(x, d, 64);
                if (t >= d) x += y;
            }
            const int basec = x - run;
            offsets[t] = basec;
#pragma unroll
            for (int w2 = 0; w2 < 16; ++w2) wcur[w2][t] += basec;
        }
        __syncthreads();
#pragma unroll
        for (int r = 0; r < 8; ++r) {
            const int p = atomicAdd(&wcur[w][my[r]], 1);
            perm[p] = r * 1024 + t;
        }
        return;
    }

    // ---------------- backbone for class c ----------------
    const int c = blockIdx.x;
    m[t] = maps[(size_t)c * 1024 + t];
    __syncthreads();

    // fc1: 1024 -> 256 (leaky); o = t&255, 4 K-slices of 256
    {
        const int o = t & 255, ks = t >> 8;
        const float* wp = fc1_w + o;
        float acc = 0.f;
#pragma unroll 8
        for (int i = 0; i < 256; ++i) {
            const int k = ks * 256 + i;
            acc += m[k] * wp[(size_t)k * 256];
        }
        red[t] = acc;
    }
    __syncthreads();
    if (t < 256)
        h1[t] = lrelu(fc1_b[t] + red[t] + red[256 + t] + red[512 + t] + red[768 + t]);
    __syncthreads();
    // fc2: 256 -> 128 (leaky); o = t&127, 8 K-slices of 32
    {
        const int o = t & 127, ks = t >> 7;
        float acc = 0.f;
#pragma unroll
        for (int i = 0; i < 32; ++i) {
            const int k = ks * 32 + i;
            acc += h1[k] * fc2_w[k * 128 + o];
        }
        red[t] = acc;
    }
    __syncthreads();
    if (t < 128) {
        float a = fc2_b[t];
#pragma unroll
        for (int r = 0; r < 8; ++r) a += red[r * 128 + t];
        h2[t] = lrelu(a);
    }
    __syncthreads();
    // fc3: 128 -> 128 (leaky); 8 K-slices of 16
    {
        const int o = t & 127, ks = t >> 7;
        float acc = 0.f;
#pragma unroll
        for (int i = 0; i < 16; ++i) {
            const int k = ks * 16 + i;
            acc += h2[k] * fc3_w[k * 128 + o];
        }
        red[t] = acc;
    }
    __syncthreads();
    if (t < 128) {
        float a = fc3_b[t];
#pragma unroll
        for (int r = 0; r < 8; ++r) a += red[r * 128 + t];
        h3[t] = lrelu(a);
    }
    __syncthreads();
    // bn: 128 -> 32 (no act); o = t&31, 32 K-slices of 4
    {
        const int o = t & 31, ks = t >> 5;
        float acc = 0.f;
#pragma unroll
        for (int i = 0; i < 4; ++i) {
            const int k = ks * 4 + i;
            acc += h3[k] * bn_w[k * 32 + o];
        }
        red[t] = acc;
    }
    __syncthreads();
    if (t < 32) {
        float a = bn_b[t];
#pragma unroll
        for (int r = 0; r < 32; ++r) a += red[r * 32 + t];
        z[c * 32 + t] = a;
    }
}

// ---------------------------------------------------------------------------
// K2: theta, grid (107, 8): block owns 256 cols x 8 classes. Weights in regs.
// ---------------------------------------------------------------------------
__global__ __launch_bounds__(256) void theta_kernel(
    const float* __restrict__ z,
    const float* __restrict__ e_w, const float* __restrict__ e_b,
    const float* __restrict__ f_w, const float* __restrict__ f_b,
    float* __restrict__ th_e, float* __restrict__ th_f)
{
    __shared__ __align__(16) float zl[2048];
    const int t = threadIdx.x;
    ((float4*)zl)[t]       = ((const float4*)z)[t];
    ((float4*)zl)[t + 256] = ((const float4*)z)[t + 256];
    __syncthreads();

    int j = blockIdx.x * 256 + t;
    const int cbase = blockIdx.y * 8;
    const float* wbase;
    float* op;
    int stride;
    float bias;
    if (j < 5456) {
        wbase = e_w + j; bias = e_b[j]; op = th_e + j; stride = 5456;
    } else {
        const int jj = j - 5456;
        if (jj >= 21768) return;
        wbase = f_w + jj; bias = f_b[jj]; op = th_f + jj; stride = 21768;
    }
    float wk[32];
#pragma unroll
    for (int k = 0; k < 32; ++k) wk[k] = wbase[(size_t)k * stride];

#pragma unroll
    for (int cc = 0; cc < 8; cc += 4) {
        const int c0 = cbase + cc;
        float a0 = bias, a1 = bias, a2 = bias, a3 = bias;
#pragma unroll
        for (int k4 = 0; k4 < 8; ++k4) {
            const float4 z0 = *(const float4*)&zl[(c0 + 0) * 32 + k4 * 4];
            const float4 z1 = *(const float4*)&zl[(c0 + 1) * 32 + k4 * 4];
            const float4 z2 = *(const float4*)&zl[(c0 + 2) * 32 + k4 * 4];
            const float4 z3 = *(const float4*)&zl[(c0 + 3) * 32 + k4 * 4];
            const float w0 = wk[k4 * 4], w1 = wk[k4 * 4 + 1];
            const float w2 = wk[k4 * 4 + 2], w3 = wk[k4 * 4 + 3];
            a0 += z0.x * w0 + z0.y * w1 + z0.z * w2 + z0.w * w3;
            a1 += z1.x * w0 + z1.y * w1 + z1.z * w2 + z1.w * w3;
            a2 += z2.x * w0 + z2.y * w1 + z2.z * w2 + z2.w * w3;
            a3 += z3.x * w0 + z3.y * w1 + z3.z * w2 + z3.w * w3;
        }
        op[(size_t)(c0 + 0) * stride] = a0;
        op[(size_t)(c0 + 1) * stride] = a1;
        op[(size_t)(c0 + 2) * stride] = a2;
        op[(size_t)(c0 + 3) * stride] = a3;
    }
}

// ---------------------------------------------------------------------------
// K3: func v4. grid (64, 4), 512 thr (8 waves). 32 batches/pass; weights
// staged once per pass (~once per block). LDS 61KB -> 1 block/CU.
//   e: vb = t&63 (32 batches x {S,G}), ge = t>>6 (8 groups x 8 cols)
//   f: b = t&31, gf = t>>5 (16 groups x 8 cols)
// ---------------------------------------------------------------------------
#define ESTRIDE 68   // 17 float4s, odd -> conflict-free across 64 vbatches
#define FSTRIDE 132  // 33 float4s, odd

__global__ __launch_bounds__(512) void func_kernel(
    const float* __restrict__ states,
    const float* __restrict__ th_e_all, const float* __restrict__ th_f_all,
    const int* __restrict__ counts, const int* __restrict__ offsets,
    const int* __restrict__ perm, float* __restrict__ out)
{
    __shared__ __align__(16) float wbuf[5392];   // e-block / f-L1 / W2f quarter
    __shared__ __align__(16) float w3fb[1160];   // b2f | W3f | b3f (persistent)
    __shared__ __align__(16) float actA[4352];
    __shared__ __align__(16) float actB[4352];

    const int c = blockIdx.x;
    const int s = blockIdx.y;
    const int nb   = counts[c];
    const int base = offsets[c];
    const int chunk = (nb + NSLICE - 1) / NSLICE;
    const int k0 = s * chunk;
    const int k1 = (nb < k0 + chunk) ? nb : (k0 + chunk);
    const int cnt = (k1 > k0) ? (k1 - k0) : 0;
    if (cnt == 0) return;

    const float* te = th_e_all + (size_t)c * 5456;
    const float* tf = th_f_all + (size_t)c * 21768;

    const int t  = threadIdx.x;
    const int b  = t & 31;           // batch slot (both views)
    const int ve = (t >> 5) & 1;     // e: S/G select
    const int vb = t & 63;           // e virtual batch
    const int ge = t >> 6;           // e col group (wave-uniform)
    const int gf = t >> 5;           // f col group (2 per wave)
    const int cole = ge * 8;
    const int colf = gf * 8;
    const int eoff = vb * ESTRIDE;
    const int foff = b * FSTRIDE;

    // persistent tail + e-weights (first pass)
    for (int j = t * 4; j < 1160; j += 2048)
        *(float4*)&w3fb[j] = *(const float4*)&tf[20608 + j];
    for (int j = t * 4; j < 5392; j += 2048)
        *(float4*)&wbuf[j] = *(const float4*)&te[j];

    const int passes = (cnt + 31) >> 5;
    for (int p = 0; p < passes; ++p) {
        __syncthreads();   // staging visible / prev-pass f-L3 reads done
        if (p) {
            for (int j = t * 4; j < 5392; j += 2048)
                *(float4*)&wbuf[j] = *(const float4*)&te[j];
            __syncthreads();
        }

        const int kk = k0 + p * 32 + b;
        const bool valid = kk < k1;
        const int bi = valid ? perm[base + kk] : 0;
        const float2 sv = *(const float2*)&states[(size_t)bi * 4 + 2 * ve];

        // ---- e-L1: 2 -> 64 (leaky) ----
        {
            const float4 wa0 = *(const float4*)&wbuf[cole];
            const float4 wa1 = *(const float4*)&wbuf[cole + 4];
            const float4 wb0 = *(const float4*)&wbuf[64 + cole];
            const float4 wb1 = *(const float4*)&wbuf[64 + cole + 4];
            const float4 bb0 = *(const float4*)&wbuf[128 + cole];
            const float4 bb1 = *(const float4*)&wbuf[128 + cole + 4];
            float4 o0, o1;
            o0.x = lrelu(sv.x * wa0.x + sv.y * wb0.x + bb0.x);
            o0.y = lrelu(sv.x * wa0.y + sv.y * wb0.y + bb0.y);
            o0.z = lrelu(sv.x * wa0.z + sv.y * wb0.z + bb0.z);
            o0.w = lrelu(sv.x * wa0.w + sv.y * wb0.w + bb0.w);
            o1.x = lrelu(sv.x * wa1.x + sv.y * wb1.x + bb1.x);
            o1.y = lrelu(sv.x * wa1.y + sv.y * wb1.y + bb1.y);
            o1.z = lrelu(sv.x * wa1.z + sv.y * wb1.z + bb1.z);
            o1.w = lrelu(sv.x * wa1.w + sv.y * wb1.w + bb1.w);
            *(float4*)&actA[eoff + cole]     = o0;
            *(float4*)&actA[eoff + cole + 4] = o1;
        }
        __syncthreads();

        // ---- e-L2: 64 -> 64 (leaky) ----
        {
            float acc[8] = {0, 0, 0, 0, 0, 0, 0, 0};
#pragma unroll 4
            for (int i4 = 0; i4 < 16; ++i4) {
                const float4 y4 = *(const float4*)&actA[eoff + i4 * 4];
#pragma unroll
                for (int u = 0; u < 4; ++u) {
                    const int row = 192 + (i4 * 4 + u) * 64 + cole;
                    const float4 wA = *(const float4*)&wbuf[row];
                    const float4 wB = *(const float4*)&wbuf[row + 4];
                    const float yv = (&y4.x)[u];
                    acc[0] += yv * wA.x; acc[1] += yv * wA.y;
                    acc[2] += yv * wA.z; acc[3] += yv * wA.w;
                    acc[4] += yv * wB.x; acc[5] += yv * wB.y;
                    acc[6] += yv * wB.z; acc[7] += yv * wB.w;
                }
            }
            const float4 bA = *(const float4*)&wbuf[4288 + cole];
            const float4 bB = *(const float4*)&wbuf[4288 + cole + 4];
            float4 o0, o1;
            o0.x = lrelu(acc[0] + bA.x); o0.y = lrelu(acc[1] + bA.y);
            o0.z = lrelu(acc[2] + bA.z); o0.w = lrelu(acc[3] + bA.w);
            o1.x = lrelu(acc[4] + bB.x); o1.y = lrelu(acc[5] + bB.y);
            o1.z = lrelu(acc[6] + bB.z); o1.w = lrelu(acc[7] + bB.w);
            *(float4*)&actB[eoff + cole]     = o0;
            *(float4*)&actB[eoff + cole + 4] = o1;
        }
        __syncthreads();

        // ---- e-L3: 64 -> 16 (no act) -> zf (f-view of actA) ----
        {
            const int col3 = ge * 2;
            float a0 = 0.f, a1 = 0.f;
#pragma unroll 4
            for (int i4 = 0; i4 < 16; ++i4) {
                const float4 y4 = *(const float4*)&actB[eoff + i4 * 4];
#pragma unroll
                for (int u = 0; u < 4; ++u) {
                    const int i = i4 * 4 + u;
                    const float yv = (&y4.x)[u];
                    a0 += yv * wbuf[4352 + i * 16 + col3];
                    a1 += yv * wbuf[4352 + i * 16 + col3 + 1];
                }
            }
            a0 += wbuf[5376 + col3];
            a1 += wbuf[5376 + col3 + 1];
            actA[foff + ve * 16 + col3]     = a0;
            actA[foff + ve * 16 + col3 + 1] = a1;
        }
        __syncthreads();

        // ---- stage f-L1 weights (tf[0..4224)) ----
        for (int j = t * 4; j < 4224; j += 2048)
            *(float4*)&wbuf[j] = *(const float4*)&tf[j];
        __syncthreads();

        // ---- f-L1: 32 -> 128 (leaky) ----
        {
            float acc[8] = {0, 0, 0, 0, 0, 0, 0, 0};
#pragma unroll
            for (int i4 = 0; i4 < 8; ++i4) {
                const float4 y4 = *(const float4*)&actA[foff + i4 * 4];
#pragma unroll
                for (int u = 0; u < 4; ++u) {
                    const int row = (i4 * 4 + u) * 128 + colf;
                    const float4 wA = *(const float4*)&wbuf[row];
                    const float4 wB = *(const float4*)&wbuf[row + 4];
                    const float yv = (&y4.x)[u];
                    acc[0] += yv * wA.x; acc[1] += yv * wA.y;
                    acc[2] += yv * wA.z; acc[3] += yv * wA.w;
                    acc[4] += yv * wB.x; acc[5] += yv * wB.y;
                    acc[6] += yv * wB.z; acc[7] += yv * wB.w;
                }
            }
            const float4 bA = *(const float4*)&wbuf[4096 + colf];
            const float4 bB = *(const float4*)&wbuf[4096 + colf + 4];
            float4 o0, o1;
            o0.x = lrelu(acc[0] + bA.x); o0.y = lrelu(acc[1] + bA.y);
            o0.z = lrelu(acc[2] + bA.z); o0.w = lrelu(acc[3] + bA.w);
            o1.x = lrelu(acc[4] + bB.x); o1.y = lrelu(acc[5] + bB.y);
            o1.z = lrelu(acc[6] + bB.z); o1.w = lrelu(acc[7] + bB.w);
            *(float4*)&actB[foff + colf]     = o0;
            *(float4*)&actB[foff + colf + 4] = o1;
        }
        __syncthreads();

        // ---- f-L2: 128 -> 128 (leaky), W2f staged in 4 K-quarters ----
        {
            float acc[8] = {0, 0, 0, 0, 0, 0, 0, 0};
#pragma unroll
            for (int h = 0; h < 4; ++h) {
                if (h) __syncthreads();   // drain prev quarter reads
                for (int j = t * 4; j < 4096; j += 2048)
                    *(float4*)&wbuf[j] = *(const float4*)&tf[4224 + h * 4096 + j];
                __syncthreads();
#pragma unroll 4
                for (int i4 = 0; i4 < 8; ++i4) {
                    const float4 y4 = *(const float4*)&actB[foff + h * 32 + i4 * 4];
#pragma unroll
                    for (int u = 0; u < 4; ++u) {
                        const int row = (i4 * 4 + u) * 128 + colf;
                        const float4 wA = *(const float4*)&wbuf[row];
                        const float4 wB = *(const float4*)&wbuf[row + 4];
                        const float yv = (&y4.x)[u];
                        acc[0] += yv * wA.x; acc[1] += yv * wA.y;
                        acc[2] += yv * wA.z; acc[3] += yv * wA.w;
                        acc[4] += yv * wB.x; acc[5] += yv * wB.y;
                        acc[6] += yv * wB.z; acc[7] += yv * wB.w;
                    }
                }
            }
            const float4 bA = *(const float4*)&w3fb[colf];
            const float4 bB = *(const float4*)&w3fb[colf + 4];
            float4 o0, o1;
            o0.x = lrelu(acc[0] + bA.x); o0.y = lrelu(acc[1] + bA.y);
            o0.z = lrelu(acc[2] + bA.z); o0.w = lrelu(acc[3] + bA.w);
            o1.x = lrelu(acc[4] + bB.x); o1.y = lrelu(acc[5] + bB.y);
            o1.z = lrelu(acc[6] + bB.z); o1.w = lrelu(acc[7] + bB.w);
            *(float4*)&actA[foff + colf]     = o0;
            *(float4*)&actA[foff + colf + 4] = o1;
        }
        __syncthreads();

        // ---- f-L3: 128 -> 8 (no act) + sin/cos ----
        if (gf < 8) {
            float a = 0.f;
#pragma unroll 8
            for (int i4 = 0; i4 < 32; ++i4) {
                const float4 y4 = *(const float4*)&actA[foff + i4 * 4];
#pragma unroll
                for (int u = 0; u < 4; ++u)
                    a += (&y4.x)[u] * w3fb[128 + (i4 * 4 + u) * 8 + gf];
            }
            a += w3fb[1152 + gf];
            if (valid) {
                out[(size_t)bi * 16 + gf]     = __sinf(a);
                out[(size_t)bi * 16 + 8 + gf] = __cosf(a);
            }
        }
    }
}

// ---------------------------------------------------------------------------
extern "C" void kernel_launch(void* const* d_in, const int* in_sizes, int n_in,
                              void* d_out, int out_size, void* d_ws, size_t ws_size,
                              hipStream_t stream)
{
    const int*   indices = (const int*)  d_in[0];
    const float* states  = (const float*)d_in[1];
    const float* maps    = (const float*)d_in[2];
    const float* fc1_w   = (const float*)d_in[3];
    const float* fc1_b   = (const float*)d_in[4];
    const float* fc2_w   = (const float*)d_in[5];
    const float* fc2_b   = (const float*)d_in[6];
    const float* fc3_w   = (const float*)d_in[7];
    const float* fc3_b   = (const float*)d_in[8];
    const float* bn_w    = (const float*)d_in[9];
    const float* bn_b    = (const float*)d_in[10];
    const float* e_w     = (const float*)d_in[11];
    const float* e_b     = (const float*)d_in[12];
    const float* f_w     = (const float*)d_in[13];
    const float* f_b     = (const float*)d_in[14];
    float* out = (float*)d_out;

    float* ws   = (float*)d_ws;
    float* z    = ws;                    // 2048
    float* th_e = ws + 2048;             // 349184
    float* th_f = ws + 351232;           // 1393152
    int* counts  = (int*)(ws + 1744384); // 64
    int* offsets = counts + 64;          // 64
    int* perm    = counts + 128;         // 8192

    backbone_bucket_kernel<<<65, 1024, 0, stream>>>(
        maps, fc1_w, fc1_b, fc2_w, fc2_b, fc3_w, fc3_b, bn_w, bn_b, z,
        indices, counts, offsets, perm);
    theta_kernel<<<dim3(107, 8), 256, 0, stream>>>(
        z, e_w, e_b, f_w, f_b, th_e, th_f);
    func_kernel<<<dim3(NCLS, NSLICE), 512, 0, stream>>>(
        states, th_e, th_f, counts, offsets, perm, out);
}